// Round 1
// baseline (528.683 us; speedup 1.0000x reference)
//
#include <hip/hip_runtime.h>

typedef unsigned short ushort_t;
typedef __bf16 bf16x8 __attribute__((ext_vector_type(8)));
typedef float f32x4 __attribute__((ext_vector_type(4)));

#define MFMA(a, b, c) __builtin_amdgcn_mfma_f32_16x16x32_bf16((a), (b), (c), 0, 0, 0)

// ---- constants for this problem ----
#define BATCH 8
#define SEQ 1024
#define CDIM 768
#define NH 12
#define HD 64
#define MTOT (BATCH * SEQ)      // 8192
#define THREEC (3 * CDIM)       // 2304
#define LOG2E 1.44269504088896f

__device__ __forceinline__ ushort_t f2bf(float f) {
    unsigned int u = __builtin_bit_cast(unsigned int, f);
    u = (u + 0x7FFFu + ((u >> 16) & 1u)) >> 16;  // RNE
    return (ushort_t)u;
}
__device__ __forceinline__ float bf2f(ushort_t b) {
    unsigned int u = ((unsigned int)b) << 16;
    return __builtin_bit_cast(float, u);
}

typedef const __attribute__((address_space(1))) unsigned int* gas_ptr;
typedef __attribute__((address_space(3))) unsigned int* las_ptr;

__device__ __forceinline__ void async16(const ushort_t* g, ushort_t* l) {
    __builtin_amdgcn_global_load_lds((gas_ptr)(const void*)g, (las_ptr)(void*)l, 16, 0, 0);
}

// ------------------- convert f32 -> bf16 (x, qkv_w, proj_w) -------------------
__global__ __launch_bounds__(256) void k_convert(const float* __restrict__ x,
                                                 const float* __restrict__ wq,
                                                 const float* __restrict__ wp,
                                                 ushort_t* __restrict__ xb,
                                                 ushort_t* __restrict__ wqb,
                                                 ushort_t* __restrict__ wpb) {
    const int NX = MTOT * CDIM / 4;       // 1572864
    const int NQ = THREEC * CDIM / 4;     // 442368
    const int NP = CDIM * CDIM / 4;       // 147456
    int i = blockIdx.x * 256 + threadIdx.x;
    const float4* src;
    ushort_t* dst;
    int off;
    if (i < NX) { src = (const float4*)x; dst = xb; off = i; }
    else if (i < NX + NQ) { src = (const float4*)wq; dst = wqb; off = i - NX; }
    else if (i < NX + NQ + NP) { src = (const float4*)wp; dst = wpb; off = i - NX - NQ; }
    else return;
    float4 v = src[off];
    ushort4 o;
    o.x = f2bf(v.x); o.y = f2bf(v.y); o.z = f2bf(v.z); o.w = f2bf(v.w);
    ((ushort4*)dst)[off] = o;
}

// ------------------- rel-pos bias table gather: biasT[h][n][m] -------------------
__global__ __launch_bounds__(256) void k_bias(const int* __restrict__ rpi,
                                              const float* __restrict__ table,
                                              ushort_t* __restrict__ biasT) {
    int i = blockIdx.x * 256 + threadIdx.x;   // 0 .. 1048575  (n*1024+m)
    int idx = rpi[i];
    const float* row = table + idx * NH;
#pragma unroll
    for (int h = 0; h < NH; h++)
        biasT[h * (SEQ * SEQ) + i] = f2bf(row[h]);
}

// ------------------- GEMM (A[M][K] bf16) x (B[Nc][K] bf16)^T -------------------
// MODE 0: qkv gemm -> scatter q (scaled,+qbias), k, vT (+vbias)
// MODE 1: proj gemm -> f32 out + proj bias
template <int MODE>
__global__ __launch_bounds__(256) void k_gemm(const ushort_t* __restrict__ A,
                                              const ushort_t* __restrict__ Bw,
                                              const float* __restrict__ biasq,
                                              const float* __restrict__ biasv,
                                              const float* __restrict__ biasp,
                                              ushort_t* __restrict__ qb,
                                              ushort_t* __restrict__ kb,
                                              ushort_t* __restrict__ vT,
                                              float* __restrict__ outp) {
    __shared__ __attribute__((aligned(16))) ushort_t As[128 * 64];
    __shared__ __attribute__((aligned(16))) ushort_t Bs[128 * 64];
    const int K = CDIM;
    int tid = threadIdx.x, wave = tid >> 6, lane = tid & 63;
    int l15 = lane & 15, lq = lane >> 4;
    int wm = wave >> 1, wn = wave & 1;
    int rowBase = blockIdx.y * 128;
    int colBase = blockIdx.x * 128;
    f32x4 acc[4][4] = {};
    int srow = wave * 8 + (lane >> 3);
    int scol = (lane & 7) * 8;        // in ushorts (16B)
    for (int k0 = 0; k0 < K; k0 += 64) {
#pragma unroll
        for (int is = 0; is < 4; is++) {
            async16(A + (rowBase + is * 32 + srow) * K + k0 + scol,
                    As + is * 2048 + wave * 512 + lane * 8);
            async16(Bw + (colBase + is * 32 + srow) * K + k0 + scol,
                    Bs + is * 2048 + wave * 512 + lane * 8);
        }
        asm volatile("s_waitcnt vmcnt(0)" ::: "memory");
        __syncthreads();
#pragma unroll
        for (int kk = 0; kk < 64; kk += 32) {
            bf16x8 af[4], bfr[4];
#pragma unroll
            for (int mf = 0; mf < 4; mf++)
                af[mf] = *(const bf16x8*)&As[(wm * 64 + mf * 16 + l15) * 64 + kk + 8 * lq];
#pragma unroll
            for (int nf = 0; nf < 4; nf++)
                bfr[nf] = *(const bf16x8*)&Bs[(wn * 64 + nf * 16 + l15) * 64 + kk + 8 * lq];
#pragma unroll
            for (int mf = 0; mf < 4; mf++)
#pragma unroll
                for (int nf = 0; nf < 4; nf++)
                    acc[mf][nf] = MFMA(af[mf], bfr[nf], acc[mf][nf]);
        }
        __syncthreads();
    }
    // epilogue
#pragma unroll
    for (int mf = 0; mf < 4; mf++) {
#pragma unroll
        for (int nf = 0; nf < 4; nf++) {
#pragma unroll
            for (int r = 0; r < 4; r++) {
                int mg = rowBase + wm * 64 + mf * 16 + lq * 4 + r;
                int jc = colBase + wn * 64 + nf * 16 + l15;
                float val = acc[mf][nf][r];
                if (MODE == 0) {
                    int which = jc / CDIM;
                    int co = jc - which * CDIM;
                    int b = mg >> 10, tok = mg & 1023;
                    int hh = co >> 6, dd = co & 63;
                    int bh = b * NH + hh;
                    if (which == 0) {
                        val = (val + biasq[co]) * 0.125f;
                        qb[(bh * SEQ + tok) * HD + dd] = f2bf(val);
                    } else if (which == 1) {
                        kb[(bh * SEQ + tok) * HD + dd] = f2bf(val);
                    } else {
                        val += biasv[co];
                        vT[(bh * HD + dd) * SEQ + tok] = f2bf(val);
                    }
                } else {
                    outp[mg * CDIM + jc] = val + biasp[jc];
                }
            }
        }
    }
}

// ------------------- fused flash attention with rel-pos bias -------------------
// grid: 768 = (b,h) * 8 q-tiles; block: 256 threads = 4 waves * 32 query rows
__global__ __launch_bounds__(256) void k_attn(const ushort_t* __restrict__ qb,
                                              const ushort_t* __restrict__ kb,
                                              const ushort_t* __restrict__ vT,
                                              const ushort_t* __restrict__ biasT,
                                              ushort_t* __restrict__ ctx) {
    __shared__ __attribute__((aligned(16))) ushort_t p_lds[4][32][128];
    int bid = blockIdx.x;
    int qt = bid & 7;
    int bh = bid >> 3;
    int b = bh / NH, h = bh - b * NH;
    int tid = threadIdx.x, wave = tid >> 6, lane = tid & 63;
    int l15 = lane & 15, lq = lane >> 4;
    int row0 = qt * 128 + wave * 32;
    const ushort_t* qp = qb + bh * SEQ * HD;
    const ushort_t* kp = kb + bh * SEQ * HD;
    const ushort_t* vp = vT + bh * HD * SEQ;
    const ushort_t* bp = biasT + h * (SEQ * SEQ);

    bf16x8 qf[2][2];
#pragma unroll
    for (int m = 0; m < 2; m++)
#pragma unroll
        for (int ks = 0; ks < 2; ks++)
            qf[m][ks] = *(const bf16x8*)&qp[(row0 + m * 16 + l15) * HD + ks * 32 + 8 * lq];

    f32x4 Oa[2][4] = {};
    float mi[2][4], li[2][4];
#pragma unroll
    for (int m = 0; m < 2; m++)
#pragma unroll
        for (int r = 0; r < 4; r++) { mi[m][r] = -1e30f; li[m][r] = 0.0f; }

    for (int c0 = 0; c0 < SEQ; c0 += 128) {
        f32x4 acc[2][8] = {};
#pragma unroll
        for (int n = 0; n < 8; n++) {
            bf16x8 kf0 = *(const bf16x8*)&kp[(c0 + n * 16 + l15) * HD + 8 * lq];
            bf16x8 kf1 = *(const bf16x8*)&kp[(c0 + n * 16 + l15) * HD + 32 + 8 * lq];
            acc[0][n] = MFMA(qf[0][0], kf0, acc[0][n]);
            acc[0][n] = MFMA(qf[0][1], kf1, acc[0][n]);
            acc[1][n] = MFMA(qf[1][0], kf0, acc[1][n]);
            acc[1][n] = MFMA(qf[1][1], kf1, acc[1][n]);
        }
        // add relative position bias
#pragma unroll
        for (int m = 0; m < 2; m++)
#pragma unroll
            for (int n = 0; n < 8; n++)
#pragma unroll
                for (int r = 0; r < 4; r++) {
                    int rg = row0 + m * 16 + lq * 4 + r;
                    int cg = c0 + n * 16 + l15;
                    acc[m][n][r] += bf2f(bp[rg * SEQ + cg]);
                }
        // online softmax (rows live across the 16 lanes of each quarter-wave)
#pragma unroll
        for (int m = 0; m < 2; m++)
#pragma unroll
            for (int r = 0; r < 4; r++) {
                float t = acc[m][0][r];
#pragma unroll
                for (int n = 1; n < 8; n++) t = fmaxf(t, acc[m][n][r]);
                t = fmaxf(t, __shfl_xor(t, 1));
                t = fmaxf(t, __shfl_xor(t, 2));
                t = fmaxf(t, __shfl_xor(t, 4));
                t = fmaxf(t, __shfl_xor(t, 8));
                float mn = fmaxf(mi[m][r], t);
                float al = exp2f((mi[m][r] - mn) * LOG2E);
                mi[m][r] = mn;
                li[m][r] *= al;
#pragma unroll
                for (int nc = 0; nc < 4; nc++) Oa[m][nc][r] *= al;
                float s = 0.0f;
#pragma unroll
                for (int n = 0; n < 8; n++) {
                    float p = exp2f((acc[m][n][r] - mn) * LOG2E);
                    acc[m][n][r] = p;
                    s += p;
                }
                s += __shfl_xor(s, 1);
                s += __shfl_xor(s, 2);
                s += __shfl_xor(s, 4);
                s += __shfl_xor(s, 8);
                li[m][r] += s;
            }
        // P -> bf16 -> per-wave LDS (re-layout for PV A-operand)
#pragma unroll
        for (int m = 0; m < 2; m++)
#pragma unroll
            for (int n = 0; n < 8; n++)
#pragma unroll
                for (int r = 0; r < 4; r++)
                    p_lds[wave][m * 16 + lq * 4 + r][n * 16 + l15] = f2bf(acc[m][n][r]);
        __syncthreads();
        // PV: O += P @ V   (V read from transposed layout vT[d][tok])
#pragma unroll
        for (int ks = 0; ks < 4; ks++) {
            bf16x8 pf0 = *(const bf16x8*)&p_lds[wave][l15][ks * 32 + 8 * lq];
            bf16x8 pf1 = *(const bf16x8*)&p_lds[wave][16 + l15][ks * 32 + 8 * lq];
#pragma unroll
            for (int nc = 0; nc < 4; nc++) {
                bf16x8 vf = *(const bf16x8*)&vp[(nc * 16 + l15) * SEQ + c0 + ks * 32 + 8 * lq];
                Oa[0][nc] = MFMA(pf0, vf, Oa[0][nc]);
                Oa[1][nc] = MFMA(pf1, vf, Oa[1][nc]);
            }
        }
        __syncthreads();
    }
    // epilogue: ctx[b][tok][h*64+dd] bf16
#pragma unroll
    for (int m = 0; m < 2; m++)
#pragma unroll
        for (int nc = 0; nc < 4; nc++)
#pragma unroll
            for (int r = 0; r < 4; r++) {
                int tok = row0 + m * 16 + lq * 4 + r;
                int dd = nc * 16 + l15;
                float val = Oa[m][nc][r] / li[m][r];
                ctx[(b * SEQ + tok) * CDIM + h * HD + dd] = f2bf(val);
            }
}

// ------------------- launcher -------------------
extern "C" void kernel_launch(void* const* d_in, const int* in_sizes, int n_in,
                              void* d_out, int out_size, void* d_ws, size_t ws_size,
                              hipStream_t stream) {
    const float* x = (const float*)d_in[0];
    const int* rpi = (const int*)d_in[1];
    const float* wqkv = (const float*)d_in[2];
    const float* qbias = (const float*)d_in[3];
    const float* vbias = (const float*)d_in[4];
    const float* wproj = (const float*)d_in[5];
    const float* pbias = (const float*)d_in[6];
    const float* table = (const float*)d_in[7];
    float* out = (float*)d_out;

    char* ws = (char*)d_ws;
    // workspace layout (bytes)
    ushort_t* xb    = (ushort_t*)(ws + 0);                       // 12,582,912
    ushort_t* wqb   = (ushort_t*)(ws + 12582912);                //  3,538,944
    ushort_t* wpb   = (ushort_t*)(ws + 16121856);                //  1,179,648
    ushort_t* qbuf  = (ushort_t*)(ws + 17301504);                // 12,582,912
    ushort_t* kbuf  = (ushort_t*)(ws + 29884416);                // 12,582,912
    ushort_t* vTbuf = (ushort_t*)(ws + 42467328);                // 12,582,912
    ushort_t* ctx   = (ushort_t*)(ws + 55050240);                // 12,582,912
    ushort_t* biasT = (ushort_t*)(ws + 67633152);                // 25,165,824  (end ~92.8MB)

    k_convert<<<8448, 256, 0, stream>>>(x, wqkv, wproj, xb, wqb, wpb);
    k_bias<<<4096, 256, 0, stream>>>(rpi, table, biasT);
    k_gemm<0><<<dim3(THREEC / 128, MTOT / 128), 256, 0, stream>>>(
        xb, wqb, qbias, vbias, nullptr, qbuf, kbuf, vTbuf, nullptr);
    k_attn<<<768, 256, 0, stream>>>(qbuf, kbuf, vTbuf, biasT, ctx);
    k_gemm<1><<<dim3(CDIM / 128, MTOT / 128), 256, 0, stream>>>(
        ctx, wpb, nullptr, nullptr, pbias, nullptr, nullptr, nullptr, out);
}

// Round 2
// 320.291 us; speedup vs baseline: 1.6506x; 1.6506x over previous
//
#include <hip/hip_runtime.h>

typedef unsigned short ushort_t;
typedef __bf16 bf16x8 __attribute__((ext_vector_type(8)));
typedef float f32x4 __attribute__((ext_vector_type(4)));

#define MFMA(a, b, c) __builtin_amdgcn_mfma_f32_16x16x32_bf16((a), (b), (c), 0, 0, 0)

// ---- constants for this problem ----
#define BATCH 8
#define SEQ 1024
#define CDIM 768
#define NH 12
#define HD 64
#define MTOT (BATCH * SEQ)      // 8192
#define THREEC (3 * CDIM)       // 2304
#define LOG2E 1.44269504088896f

__device__ __forceinline__ ushort_t f2bf(float f) {
    unsigned int u = __builtin_bit_cast(unsigned int, f);
    u = (u + 0x7FFFu + ((u >> 16) & 1u)) >> 16;  // RNE
    return (ushort_t)u;
}
__device__ __forceinline__ float bf2f(ushort_t b) {
    unsigned int u = ((unsigned int)b) << 16;
    return __builtin_bit_cast(float, u);
}

typedef const __attribute__((address_space(1))) unsigned int* gas_ptr;
typedef __attribute__((address_space(3))) unsigned int* las_ptr;

__device__ __forceinline__ void async16(const ushort_t* g, ushort_t* l) {
    __builtin_amdgcn_global_load_lds((gas_ptr)(const void*)g, (las_ptr)(void*)l, 16, 0, 0);
}

// ------------------- convert f32 -> bf16 (x, qkv_w, proj_w) -------------------
__global__ __launch_bounds__(256) void k_convert(const float* __restrict__ x,
                                                 const float* __restrict__ wq,
                                                 const float* __restrict__ wp,
                                                 ushort_t* __restrict__ xb,
                                                 ushort_t* __restrict__ wqb,
                                                 ushort_t* __restrict__ wpb) {
    const int NX = MTOT * CDIM / 4;       // 1572864
    const int NQ = THREEC * CDIM / 4;     // 442368
    const int NP = CDIM * CDIM / 4;       // 147456
    int i = blockIdx.x * 256 + threadIdx.x;
    const float4* src;
    ushort_t* dst;
    int off;
    if (i < NX) { src = (const float4*)x; dst = xb; off = i; }
    else if (i < NX + NQ) { src = (const float4*)wq; dst = wqb; off = i - NX; }
    else if (i < NX + NQ + NP) { src = (const float4*)wp; dst = wpb; off = i - NX - NQ; }
    else return;
    float4 v = src[off];
    ushort4 o;
    o.x = f2bf(v.x); o.y = f2bf(v.y); o.z = f2bf(v.z); o.w = f2bf(v.w);
    ((ushort4*)dst)[off] = o;
}

// ---------- rel-pos bias in MFMA fragment layout: biasF[h][tr][tc][lane][r] ----------
// grid: (64 tr, 16 tcq), 256 threads. Each 64-lane group writes one 16x16 frag per h,
// fully coalesced 8B stores.
__global__ __launch_bounds__(256) void k_bias(const int* __restrict__ rpi,
                                              const float* __restrict__ table,
                                              ushort_t* __restrict__ biasF) {
    __shared__ int idx_s[16][64];
    int tr = blockIdx.x;      // row tile 0..63
    int tcq = blockIdx.y;     // col quad 0..15
    int t = threadIdx.x;
    {
        int r = t >> 4;                // 0..15
        int c4 = (t & 15) * 4;         // 0..60
        int4 v = *(const int4*)&rpi[(tr * 16 + r) * SEQ + tcq * 64 + c4];
        *(int4*)&idx_s[r][c4] = v;
    }
    __syncthreads();
    int j = t >> 6;                    // tile within quad 0..3
    int lane = t & 63;
    int lq = lane >> 4, l15 = lane & 15;
    int col = j * 16 + l15;
    int tc = tcq * 4 + j;
    int id[4];
#pragma unroll
    for (int rr = 0; rr < 4; rr++) id[rr] = idx_s[lq * 4 + rr][col];
#pragma unroll
    for (int h = 0; h < NH; h++) {
        ushort4 o;
        o.x = f2bf(table[id[0] * NH + h]);
        o.y = f2bf(table[id[1] * NH + h]);
        o.z = f2bf(table[id[2] * NH + h]);
        o.w = f2bf(table[id[3] * NH + h]);
        *(ushort4*)&biasF[(((h * 64 + tr) * 64 + tc) * 256 + lane * 4)] = o;
    }
}

// ------------------- GEMM (A[M][K] bf16) x (B[Nc][K] bf16)^T -------------------
template <int MODE>
__global__ __launch_bounds__(256) void k_gemm(const ushort_t* __restrict__ A,
                                              const ushort_t* __restrict__ Bw,
                                              const float* __restrict__ biasq,
                                              const float* __restrict__ biasv,
                                              const float* __restrict__ biasp,
                                              ushort_t* __restrict__ qb,
                                              ushort_t* __restrict__ kb,
                                              ushort_t* __restrict__ vT,
                                              float* __restrict__ outp) {
    __shared__ __attribute__((aligned(16))) ushort_t As[128 * 64];
    __shared__ __attribute__((aligned(16))) ushort_t Bs[128 * 64];
    const int K = CDIM;
    int tid = threadIdx.x, wave = tid >> 6, lane = tid & 63;
    int l15 = lane & 15, lq = lane >> 4;
    int wm = wave >> 1, wn = wave & 1;
    int rowBase = blockIdx.y * 128;
    int colBase = blockIdx.x * 128;
    f32x4 acc[4][4] = {};
    int srow = wave * 8 + (lane >> 3);
    int scol = (lane & 7) * 8;
    for (int k0 = 0; k0 < K; k0 += 64) {
#pragma unroll
        for (int is = 0; is < 4; is++) {
            async16(A + (rowBase + is * 32 + srow) * K + k0 + scol,
                    As + is * 2048 + wave * 512 + lane * 8);
            async16(Bw + (colBase + is * 32 + srow) * K + k0 + scol,
                    Bs + is * 2048 + wave * 512 + lane * 8);
        }
        asm volatile("s_waitcnt vmcnt(0)" ::: "memory");
        __syncthreads();
#pragma unroll
        for (int kk = 0; kk < 64; kk += 32) {
            bf16x8 af[4], bfr[4];
#pragma unroll
            for (int mf = 0; mf < 4; mf++)
                af[mf] = *(const bf16x8*)&As[(wm * 64 + mf * 16 + l15) * 64 + kk + 8 * lq];
#pragma unroll
            for (int nf = 0; nf < 4; nf++)
                bfr[nf] = *(const bf16x8*)&Bs[(wn * 64 + nf * 16 + l15) * 64 + kk + 8 * lq];
#pragma unroll
            for (int mf = 0; mf < 4; mf++)
#pragma unroll
                for (int nf = 0; nf < 4; nf++)
                    acc[mf][nf] = MFMA(af[mf], bfr[nf], acc[mf][nf]);
        }
        __syncthreads();
    }
#pragma unroll
    for (int mf = 0; mf < 4; mf++) {
#pragma unroll
        for (int nf = 0; nf < 4; nf++) {
#pragma unroll
            for (int r = 0; r < 4; r++) {
                int mg = rowBase + wm * 64 + mf * 16 + lq * 4 + r;
                int jc = colBase + wn * 64 + nf * 16 + l15;
                float val = acc[mf][nf][r];
                if (MODE == 0) {
                    int which = jc / CDIM;
                    int co = jc - which * CDIM;
                    int b = mg >> 10, tok = mg & 1023;
                    int hh = co >> 6, dd = co & 63;
                    int bh = b * NH + hh;
                    if (which == 0) {
                        val = (val + biasq[co]) * 0.125f;
                        qb[(bh * SEQ + tok) * HD + dd] = f2bf(val);
                    } else if (which == 1) {
                        kb[(bh * SEQ + tok) * HD + dd] = f2bf(val);
                    } else {
                        val += biasv[co];
                        vT[(bh * HD + dd) * SEQ + tok] = f2bf(val);
                    }
                } else {
                    outp[mg * CDIM + jc] = val + biasp[jc];
                }
            }
        }
    }
}

// ------------------- fused flash attention with rel-pos bias -------------------
// grid: 1536 = (bh 96) * 16 q-tiles of 64 rows; block: 256 = 4 waves * 16 query rows
__global__ __launch_bounds__(256) void k_attn(const ushort_t* __restrict__ qb,
                                              const ushort_t* __restrict__ kb,
                                              const ushort_t* __restrict__ vT,
                                              const ushort_t* __restrict__ biasF,
                                              ushort_t* __restrict__ ctx) {
    __shared__ __attribute__((aligned(16))) ushort_t p_lds[4][16][136];
    int bid = blockIdx.x;
    int qt = bid & 15;
    int bh = bid >> 4;
    int b = bh / NH, h = bh - b * NH;
    int tid = threadIdx.x, wave = tid >> 6, lane = tid & 63;
    int l15 = lane & 15, lq = lane >> 4;
    int row0 = qt * 64 + wave * 16;
    const ushort_t* qp = qb + bh * SEQ * HD;
    const ushort_t* kp = kb + bh * SEQ * HD;
    const ushort_t* vp = vT + bh * HD * SEQ;
    const ushort_t* bfp = biasF + (h * 64 + (row0 >> 4)) * 64 * 256;  // this row-tile, all col-tiles

    bf16x8 qf0 = *(const bf16x8*)&qp[(row0 + l15) * HD + 8 * lq];
    bf16x8 qf1 = *(const bf16x8*)&qp[(row0 + l15) * HD + 32 + 8 * lq];

    f32x4 Oa[4] = {};
    float mi[4], li[4];
#pragma unroll
    for (int r = 0; r < 4; r++) { mi[r] = -1e30f; li[r] = 0.0f; }

    for (int c0 = 0; c0 < SEQ; c0 += 128) {
        int ct0 = c0 >> 4;
        // bias fragments: one coalesced 8B load per 16x16 tile
        ushort4 bfrag[8];
#pragma unroll
        for (int n = 0; n < 8; n++)
            bfrag[n] = *(const ushort4*)&bfp[(ct0 + n) * 256 + lane * 4];
        // QK^T
        f32x4 acc[8] = {};
#pragma unroll
        for (int n = 0; n < 8; n++) {
            bf16x8 kf0 = *(const bf16x8*)&kp[(c0 + n * 16 + l15) * HD + 8 * lq];
            bf16x8 kf1 = *(const bf16x8*)&kp[(c0 + n * 16 + l15) * HD + 32 + 8 * lq];
            acc[n] = MFMA(qf0, kf0, acc[n]);
            acc[n] = MFMA(qf1, kf1, acc[n]);
        }
        // + bias
#pragma unroll
        for (int n = 0; n < 8; n++) {
            acc[n][0] += bf2f(bfrag[n].x);
            acc[n][1] += bf2f(bfrag[n].y);
            acc[n][2] += bf2f(bfrag[n].z);
            acc[n][3] += bf2f(bfrag[n].w);
        }
        // online softmax (row = 16 lanes of quarter-wave x 8 regs)
#pragma unroll
        for (int r = 0; r < 4; r++) {
            float t = acc[0][r];
#pragma unroll
            for (int n = 1; n < 8; n++) t = fmaxf(t, acc[n][r]);
            t = fmaxf(t, __shfl_xor(t, 1));
            t = fmaxf(t, __shfl_xor(t, 2));
            t = fmaxf(t, __shfl_xor(t, 4));
            t = fmaxf(t, __shfl_xor(t, 8));
            float mn = fmaxf(mi[r], t);
            float al = exp2f((mi[r] - mn) * LOG2E);
            mi[r] = mn;
            li[r] *= al;
#pragma unroll
            for (int nc = 0; nc < 4; nc++) Oa[nc][r] *= al;
            float s = 0.0f;
#pragma unroll
            for (int n = 0; n < 8; n++) {
                float p = exp2f((acc[n][r] - mn) * LOG2E);
                acc[n][r] = p;
                s += p;
            }
            s += __shfl_xor(s, 1);
            s += __shfl_xor(s, 2);
            s += __shfl_xor(s, 4);
            s += __shfl_xor(s, 8);
            li[r] += s;
        }
        // P -> bf16 -> per-wave LDS (no cross-wave sharing, no barrier needed)
#pragma unroll
        for (int n = 0; n < 8; n++)
#pragma unroll
            for (int r = 0; r < 4; r++)
                p_lds[wave][lq * 4 + r][n * 16 + l15] = f2bf(acc[n][r]);
        // PV: O += P @ V  (V from transposed layout vT[d][tok])
#pragma unroll
        for (int ks = 0; ks < 4; ks++) {
            bf16x8 pf = *(const bf16x8*)&p_lds[wave][l15][ks * 32 + 8 * lq];
#pragma unroll
            for (int nc = 0; nc < 4; nc++) {
                bf16x8 vf = *(const bf16x8*)&vp[(nc * 16 + l15) * SEQ + c0 + ks * 32 + 8 * lq];
                Oa[nc] = MFMA(pf, vf, Oa[nc]);
            }
        }
    }
    // epilogue: ctx[b][tok][h*64+dd] bf16
#pragma unroll
    for (int nc = 0; nc < 4; nc++)
#pragma unroll
        for (int r = 0; r < 4; r++) {
            int tok = row0 + lq * 4 + r;
            int dd = nc * 16 + l15;
            float val = Oa[nc][r] / li[r];
            ctx[(b * SEQ + tok) * CDIM + h * HD + dd] = f2bf(val);
        }
}

// ------------------- launcher -------------------
extern "C" void kernel_launch(void* const* d_in, const int* in_sizes, int n_in,
                              void* d_out, int out_size, void* d_ws, size_t ws_size,
                              hipStream_t stream) {
    const float* x = (const float*)d_in[0];
    const int* rpi = (const int*)d_in[1];
    const float* wqkv = (const float*)d_in[2];
    const float* qbias = (const float*)d_in[3];
    const float* vbias = (const float*)d_in[4];
    const float* wproj = (const float*)d_in[5];
    const float* pbias = (const float*)d_in[6];
    const float* table = (const float*)d_in[7];
    float* out = (float*)d_out;

    char* ws = (char*)d_ws;
    ushort_t* xb    = (ushort_t*)(ws + 0);                       // 12,582,912
    ushort_t* wqb   = (ushort_t*)(ws + 12582912);                //  3,538,944
    ushort_t* wpb   = (ushort_t*)(ws + 16121856);                //  1,179,648
    ushort_t* qbuf  = (ushort_t*)(ws + 17301504);                // 12,582,912
    ushort_t* kbuf  = (ushort_t*)(ws + 29884416);                // 12,582,912
    ushort_t* vTbuf = (ushort_t*)(ws + 42467328);                // 12,582,912
    ushort_t* ctx   = (ushort_t*)(ws + 55050240);                // 12,582,912
    ushort_t* biasF = (ushort_t*)(ws + 67633152);                // 25,165,824  (end ~92.8MB)

    k_convert<<<8448, 256, 0, stream>>>(x, wqkv, wproj, xb, wqb, wpb);
    k_bias<<<dim3(64, 16), 256, 0, stream>>>(rpi, table, biasF);
    k_gemm<0><<<dim3(THREEC / 128, MTOT / 128), 256, 0, stream>>>(
        xb, wqb, qbias, vbias, nullptr, qbuf, kbuf, vTbuf, nullptr);
    k_attn<<<1536, 256, 0, stream>>>(qbuf, kbuf, vTbuf, biasF, ctx);
    k_gemm<1><<<dim3(CDIM / 128, MTOT / 128), 256, 0, stream>>>(
        ctx, wpb, nullptr, nullptr, pbias, nullptr, nullptr, nullptr, out);
}